// Round 8
// baseline (918.594 us; speedup 1.0000x reference)
//
#include <hip/hip_runtime.h>

// CeNN layer, bf16 MFMA implicit GEMM, v8.
// Key change: state carried as TWO planes: s (f32 NHWC) + nl = bf16(nonlin(s))
// (NHWC). Iteration staging of nl is a pure 16B global_load_lds DMA with
// pre-swizzled per-lane global addresses (LDS linear). OOB halo -> zero pad.
// Falls back to v6 (in-staging convert) if ws_size < 201.4 MB.
// Iter: dst = 0.9*s + 0.1*conv3x3(nl, A_w) + ICp

typedef short  bf16x8 __attribute__((ext_vector_type(8)));
typedef float  f32x4  __attribute__((ext_vector_type(4)));

#define HH 128
#define WW 128
#define NCH 64
#define GROWS 8
#define NSLOT 10               // rows y0-1 .. y0+8
#define XS 32                  // output strip width
#define NC 34                  // staged cols x0-1 .. x0+32
#define ROWB 128               // 64 cin * 2B
#define SLOTB (NC * ROWB)      // 4352
#define NGRAN (NSLOT * NC * 8) // 2720 16B granules
#define ACTB_PAD 45056         // 2816 granules (pad for DMA tail)
#define WSETB 73728            // one frag-ordered bf16 weight set

__device__ __align__(16) unsigned char g_fw[3 * WSETB];

__device__ __forceinline__ float nonlin(float x) {
    const float A = 0.01f;
    float y = fminf(x, fmaf(A, x, 1.0f - A));
    return fmaxf(y, fmaf(A, y, -(1.0f - A)));
}
__device__ __forceinline__ unsigned int f2bf(float f) {
    unsigned int u = __float_as_uint(f);
    u += 0x7fffu + ((u >> 16) & 1u);       // RNE
    return u >> 16;
}
__device__ __forceinline__ void gload_lds16(const void* g, void* l) {
    __builtin_amdgcn_global_load_lds(
        (const __attribute__((address_space(1))) void*)g,
        (__attribute__((address_space(3))) void*)l, 16, 0, 0);
}

// w[cout][cin][3x3] -> fragment order; also zero the DMA pad buffer.
__global__ __launch_bounds__(256)
void prep_w(const float* __restrict__ rw, const float* __restrict__ bw,
            const float* __restrict__ aw, float* __restrict__ zpad) {
    if (zpad && blockIdx.x == 0 && blockIdx.y == 0 && threadIdx.x < 64)
        zpad[threadIdx.x] = 0.0f;
    const float* w = blockIdx.x == 0 ? rw : (blockIdx.x == 1 ? bw : aw);
    unsigned char* o = g_fw + blockIdx.x * WSETB;
    int chunk = blockIdx.y * 256 + threadIdx.x;        // 0..4607
    int cb  = chunk / 1152;
    int rem = chunk - cb * 1152;
    int kb  = rem >> 6;
    int ln  = rem & 63;
    int cout = cb * 16 + (ln & 15);
    int g    = ln >> 4;
    unsigned int h[8];
    #pragma unroll
    for (int j = 0; j < 8; ++j) {
        int k = kb * 32 + g * 8 + j;
        int tap = k >> 6;
        int cin = k & 63;
        h[j] = f2bf(w[(cout * 64 + cin) * 9 + tap]);
    }
    uint4 v;
    v.x = h[0] | (h[1] << 16);
    v.y = h[2] | (h[3] << 16);
    v.z = h[4] | (h[5] << 16);
    v.w = h[6] | (h[7] << 16);
    *(uint4*)(o + chunk * 16) = v;
}

__device__ __forceinline__ void conv_tile(const char* actl, const unsigned char* fw,
                                          int lane, int wv, f32x4 (&acc)[4][4]) {
    const int l15 = lane & 15;
    const int g4  = lane >> 4;
    #pragma unroll
    for (int kb = 0; kb < 18; ++kb) {
        const int tap  = kb >> 1;
        const int dy   = tap / 3;
        const int dx   = tap - dy * 3;
        const int cinB = (kb & 1) * 64 + g4 * 16;
        bf16x8 af[4];
        #pragma unroll
        for (int cb = 0; cb < 4; ++cb)
            af[cb] = *(const bf16x8*)(fw + ((cb * 18 + kb) * 64 + lane) * 16);
        bf16x8 bfr[4];
        #pragma unroll
        for (int i = 0; i < 4; ++i) {
            int row = wv * 2 + (i >> 1) + dy;
            int c   = (i & 1) * 16 + l15 + dx;
            bfr[i] = *(const bf16x8*)(actl + row * SLOTB + c * ROWB
                                      + (cinB ^ ((c & 7) << 4)));
        }
        #pragma unroll
        for (int cb = 0; cb < 4; ++cb)
            #pragma unroll
            for (int i = 0; i < 4; ++i)
                acc[cb][i] = __builtin_amdgcn_mfma_f32_16x16x32_bf16(
                    af[cb], bfr[i], acc[cb][i], 0, 0, 0);
    }
}

// MODE 0: init: src=x (NCHW). dst=state0 f32 NHWC; dst2=ICp; nldst=nl(state0).
// MODE 1: iter: conv input = nl plane (DMA) or nonlin(src) (legacy).
//         dst = 0.1*conv + 0.9*src + icp ; nldst = bf16(nonlin(dst)).
// MODE 2: final iter: as MODE 1 + nonlin, dst written NCHW, no nldst.
template<int MODE, int DMA>
__global__ __launch_bounds__(256, 3)
void cenn(const float* __restrict__ src,
          const unsigned short* __restrict__ nlsrc,
          const float* __restrict__ rb, const float* __restrict__ bb,
          const float* __restrict__ zz, const float* __restrict__ ab,
          const float* __restrict__ icp,
          const float* __restrict__ zpad,
          float* __restrict__ dst, float* __restrict__ dst2,
          unsigned short* __restrict__ nldst)
{
    __shared__ __align__(16) char actl[ACTB_PAD];
    const int tid  = threadIdx.x;
    const int lane = tid & 63;
    const int wv   = tid >> 6;
    const int l15  = lane & 15;
    const int g4   = lane >> 4;

    // XCD-aware bijective swizzle: 1024 blocks, 128 per XCD chunk (2 images).
    int lin = (blockIdx.z * 16 + blockIdx.y) * 4 + blockIdx.x;
    lin = (lin & 7) * 128 + (lin >> 3);
    const int x0 = (lin & 3) * XS;
    const int y0 = ((lin >> 2) & 15) * GROWS;
    const int n  = lin >> 6;

    if constexpr (MODE == 0) {
        // ---- NCHW staging of x (raw, no nonlin): runs once ----
        for (int idx = tid; idx < NSLOT * NC * 8; idx += 256) {
            int r   = idx / (NC * 8);
            int rem = idx - r * (NC * 8);
            int cb8 = rem / NC;
            int c   = rem - cb8 * NC;
            int y   = y0 + r - 1;
            int x   = x0 + c - 1;
            uint4 v = {0u, 0u, 0u, 0u};
            if ((unsigned)y < (unsigned)HH && (unsigned)x < (unsigned)WW) {
                const float* p = src + ((size_t)(n * NCH + cb8 * 8) * HH + y) * WW + x;
                unsigned int h[8];
                #pragma unroll
                for (int j = 0; j < 8; ++j)
                    h[j] = f2bf(p[(size_t)j * HH * WW]);
                v.x = h[0] | (h[1] << 16);
                v.y = h[2] | (h[3] << 16);
                v.z = h[4] | (h[5] << 16);
                v.w = h[6] | (h[7] << 16);
            }
            *(uint4*)(actl + r * SLOTB + c * ROWB + ((cb8 * 16) ^ ((c & 7) << 4))) = v;
        }
    } else if constexpr (DMA) {
        // ---- pure DMA staging of the pre-nonlin'd bf16 nl plane ----
        // LDS linear granule idx = (r*NC + c)*8 + q' ; global chan-block q = q'^(c&7).
        #pragma unroll
        for (int j = 0; j < 11; ++j) {
            int idx = j * 256 + tid;
            const void* ga = zpad;
            if (idx < NGRAN) {
                int q1  = idx & 7;
                int cc  = (idx >> 3) % NC;
                int r   = idx / (NC * 8);
                int q   = q1 ^ (cc & 7);
                int y   = y0 + r - 1;
                int x   = x0 + cc - 1;
                if ((unsigned)y < (unsigned)HH && (unsigned)x < (unsigned)WW)
                    ga = (const char*)nlsrc + ((((size_t)n * HH + y) * WW + x) << 7) + q * 16;
            }
            // wave-uniform LDS base; HW adds lane*16
            gload_lds16(ga, actl + (j * 256 + wv * 64) * 16);
        }
    } else {
        // ---- legacy staging: f32 state -> nonlin -> bf16 pack (v6 path) ----
        for (int idx = tid; idx < NSLOT * NC * 16; idx += 256) {
            int r   = idx / (NC * 16);
            int rem = idx - r * (NC * 16);
            int c   = rem >> 4;
            int q   = rem & 15;
            int y   = y0 + r - 1;
            int x   = x0 + c - 1;
            uint2 w2 = {0u, 0u};
            if ((unsigned)y < (unsigned)HH && (unsigned)x < (unsigned)WW) {
                f32x4 v = *(const f32x4*)(src + ((((size_t)n * HH + y) * WW + x) << 6) + q * 4);
                w2.x = f2bf(nonlin(v[0])) | (f2bf(nonlin(v[1])) << 16);
                w2.y = f2bf(nonlin(v[2])) | (f2bf(nonlin(v[3])) << 16);
            }
            *(uint2*)(actl + r * SLOTB + c * ROWB + ((q * 8) ^ ((c & 7) << 4))) = w2;
        }
    }
    __syncthreads();

    f32x4 acc[4][4];
    #pragma unroll
    for (int a = 0; a < 4; ++a)
        #pragma unroll
        for (int b = 0; b < 4; ++b)
            acc[a][b] = (f32x4){0.f, 0.f, 0.f, 0.f};

    conv_tile(actl, g_fw + (MODE == 0 ? 0 : 2 * WSETB), lane, wv, acc);

    // D map per acc[cb][i]: pixel = l15, couts cb*16+g4*4 + r (contiguous)
    if constexpr (MODE == 0) {
        #pragma unroll
        for (int cb = 0; cb < 4; ++cb)
            #pragma unroll
            for (int i = 0; i < 4; ++i) {
                int y  = y0 + wv * 2 + (i >> 1);
                int x  = x0 + (i & 1) * 16 + l15;
                int c0 = cb * 16 + g4 * 4;
                size_t pix = ((size_t)n * HH + y) * WW + x;
                f32x4 o;
                #pragma unroll
                for (int r = 0; r < 4; ++r) o[r] = acc[cb][i][r] + rb[c0 + r];
                *(f32x4*)(dst + (pix << 6) + c0) = o;
                if constexpr (DMA) {
                    uint2 w2;
                    w2.x = f2bf(nonlin(o[0])) | (f2bf(nonlin(o[1])) << 16);
                    w2.y = f2bf(nonlin(o[2])) | (f2bf(nonlin(o[3])) << 16);
                    *(uint2*)(nldst + (pix << 6) + c0) = w2;
                }
            }
        #pragma unroll
        for (int a = 0; a < 4; ++a)
            #pragma unroll
            for (int b = 0; b < 4; ++b)
                acc[a][b] = (f32x4){0.f, 0.f, 0.f, 0.f};
        conv_tile(actl, g_fw + WSETB, lane, wv, acc);
        #pragma unroll
        for (int cb = 0; cb < 4; ++cb)
            #pragma unroll
            for (int i = 0; i < 4; ++i) {
                int y  = y0 + wv * 2 + (i >> 1);
                int x  = x0 + (i & 1) * 16 + l15;
                int c0 = cb * 16 + g4 * 4;
                size_t base = ((((size_t)n * HH + y) * WW + x) << 6) + c0;
                f32x4 o;
                #pragma unroll
                for (int r = 0; r < 4; ++r)
                    o[r] = 0.1f * (acc[cb][i][r] + bb[c0 + r] + zz[c0 + r] + ab[c0 + r]);
                *(f32x4*)(dst2 + base) = o;
            }
    } else {
        #pragma unroll
        for (int cb = 0; cb < 4; ++cb)
            #pragma unroll
            for (int i = 0; i < 4; ++i) {
                int y  = y0 + wv * 2 + (i >> 1);
                int x  = x0 + (i & 1) * 16 + l15;
                int c0 = cb * 16 + g4 * 4;
                size_t pix = ((size_t)n * HH + y) * WW + x;
                f32x4 s = *(const f32x4*)(src + (pix << 6) + c0);
                f32x4 p = *(const f32x4*)(icp + (pix << 6) + c0);
                if constexpr (MODE == 1) {
                    f32x4 o;
                    #pragma unroll
                    for (int r = 0; r < 4; ++r)
                        o[r] = 0.1f * acc[cb][i][r] + 0.9f * s[r] + p[r];
                    *(f32x4*)(dst + (pix << 6) + c0) = o;
                    if constexpr (DMA) {
                        uint2 w2;
                        w2.x = f2bf(nonlin(o[0])) | (f2bf(nonlin(o[1])) << 16);
                        w2.y = f2bf(nonlin(o[2])) | (f2bf(nonlin(o[3])) << 16);
                        *(uint2*)(nldst + (pix << 6) + c0) = w2;
                    }
                } else {
                    #pragma unroll
                    for (int r = 0; r < 4; ++r) {
                        float v = 0.1f * acc[cb][i][r] + 0.9f * s[r] + p[r];
                        v = nonlin(v);
                        dst[((size_t)(n * NCH + c0 + r) * HH + y) * WW + x] = v;
                    }
                }
            }
    }
}

extern "C" void kernel_launch(void* const* d_in, const int* in_sizes, int n_in,
                              void* d_out, int out_size, void* d_ws, size_t ws_size,
                              hipStream_t stream) {
    const float* x  = (const float*)d_in[0];
    const float* rw = (const float*)d_in[1];
    const float* rb = (const float*)d_in[2];
    const float* aw = (const float*)d_in[3];
    const float* ab = (const float*)d_in[4];
    const float* bw = (const float*)d_in[5];
    const float* bb = (const float*)d_in[6];
    const float* z  = (const float*)d_in[7];
    float* out = (float*)d_out;

    const size_t P = (size_t)16 * NCH * HH * WW;       // 16.78M elems
    float* icp = (float*)d_ws;                          // f32 NHWC
    float* s1  = icp + P;                               // f32 NHWC ping
    unsigned short* nlA = (unsigned short*)(s1 + P);    // bf16 NHWC
    unsigned short* nlB = nlA + P;
    float* zp  = (float*)(nlB + P);                     // 256 B zero pad
    const size_t NEED = 4 * P + 4 * P + 2 * P + 2 * P + 256;
    const bool dma = ws_size >= NEED;

    dim3 blk(256, 1, 1), grd(4, 16, 16);   // 1024 blocks

    prep_w<<<dim3(3, 18, 1), blk, 0, stream>>>(rw, bw, aw, dma ? zp : nullptr);

    if (dma) {
        cenn<0, 1><<<grd, blk, 0, stream>>>(x, nullptr, rb, bb, z, ab, nullptr, zp, out, icp, nlA);
        for (int i = 0; i < 10; ++i) {
            const float* s          = (i & 1) ? s1 : out;
            const unsigned short* ns = (i & 1) ? nlB : nlA;
            float* d                = (i & 1) ? out : s1;
            unsigned short* nd      = (i & 1) ? nlA : nlB;
            if (i == 9)
                cenn<2, 1><<<grd, blk, 0, stream>>>(s, ns, nullptr, nullptr, nullptr, nullptr, icp, zp, out, nullptr, nullptr);
            else
                cenn<1, 1><<<grd, blk, 0, stream>>>(s, ns, nullptr, nullptr, nullptr, nullptr, icp, zp, d, nullptr, nd);
        }
    } else {
        cenn<0, 0><<<grd, blk, 0, stream>>>(x, nullptr, rb, bb, z, ab, nullptr, nullptr, out, icp, nullptr);
        for (int i = 0; i < 10; ++i) {
            const float* s = (i & 1) ? s1 : out;
            float*       d = (i & 1) ? out : s1;
            if (i == 9)
                cenn<2, 0><<<grd, blk, 0, stream>>>(s, nullptr, nullptr, nullptr, nullptr, nullptr, icp, nullptr, out, nullptr, nullptr);
            else
                cenn<1, 0><<<grd, blk, 0, stream>>>(s, nullptr, nullptr, nullptr, nullptr, nullptr, icp, nullptr, d, nullptr, nullptr);
        }
    }
}

// Round 9
// 619.880 us; speedup vs baseline: 1.4819x; 1.4819x over previous
//
#include <hip/hip_runtime.h>

// CeNN layer, bf16 MFMA implicit GEMM, v9 = v6 + LDS-transpose epilogue.
// Iteration epilogue: conv acc -> LDS (b128, XOR-swizzled) -> read back in
// NHWC streaming order so all epilogue global loads/stores are contiguous
// 1KB/wave instructions. MODE2 adds a second LDS pass for contiguous NCHW.
// Iter: dst = 0.9*src + 0.1*conv3x3(nonlin(src), A_w) + ICp

typedef short  bf16x8 __attribute__((ext_vector_type(8)));
typedef float  f32x4  __attribute__((ext_vector_type(4)));

#define HH 128
#define WW 128
#define NCH 64
#define GROWS 8
#define NSLOT 10               // rows y0-1 .. y0+8
#define XS 32                  // output strip width
#define NC 34                  // staged cols x0-1 .. x0+32
#define ROWB 128               // 64 cin * 2B
#define SLOTB (NC * ROWB)      // 4352
#define ACTB (NSLOT * SLOTB)   // 43520 (>= 32768 transpose chunk)
#define WSETB 73728            // one frag-ordered bf16 weight set

__device__ __align__(16) unsigned char g_fw[3 * WSETB];

__device__ __forceinline__ float nonlin(float x) {
    const float A = 0.01f;
    float y = fminf(x, fmaf(A, x, 1.0f - A));
    return fmaxf(y, fmaf(A, y, -(1.0f - A)));
}
__device__ __forceinline__ unsigned int f2bf(float f) {
    unsigned int u = __float_as_uint(f);
    u += 0x7fffu + ((u >> 16) & 1u);       // RNE
    return u >> 16;
}

// w[cout][cin][3x3] -> fragment order. chunk=(cb*18+kb)*64+ln ;
// value j: k = kb*32+(ln>>4)*8+j ; k = tap*64+cin.
__global__ __launch_bounds__(256)
void prep_w(const float* __restrict__ rw, const float* __restrict__ bw,
            const float* __restrict__ aw) {
    const float* w = blockIdx.x == 0 ? rw : (blockIdx.x == 1 ? bw : aw);
    unsigned char* o = g_fw + blockIdx.x * WSETB;
    int chunk = blockIdx.y * 256 + threadIdx.x;        // 0..4607
    int cb  = chunk / 1152;
    int rem = chunk - cb * 1152;
    int kb  = rem >> 6;
    int ln  = rem & 63;
    int cout = cb * 16 + (ln & 15);
    int g    = ln >> 4;
    unsigned int h[8];
    #pragma unroll
    for (int j = 0; j < 8; ++j) {
        int k = kb * 32 + g * 8 + j;
        int tap = k >> 6;
        int cin = k & 63;
        h[j] = f2bf(w[(cout * 64 + cin) * 9 + tap]);
    }
    uint4 v;
    v.x = h[0] | (h[1] << 16);
    v.y = h[2] | (h[3] << 16);
    v.z = h[4] | (h[5] << 16);
    v.w = h[6] | (h[7] << 16);
    *(uint4*)(o + chunk * 16) = v;
}

__device__ __forceinline__ void conv_tile(const char* actl, const unsigned char* fw,
                                          int lane, int wv, f32x4 (&acc)[4][4]) {
    const int l15 = lane & 15;
    const int g4  = lane >> 4;
    #pragma unroll
    for (int kb = 0; kb < 18; ++kb) {
        const int tap  = kb >> 1;
        const int dy   = tap / 3;
        const int dx   = tap - dy * 3;
        const int cinB = (kb & 1) * 64 + g4 * 16;
        bf16x8 af[4];
        #pragma unroll
        for (int cb = 0; cb < 4; ++cb)
            af[cb] = *(const bf16x8*)(fw + ((cb * 18 + kb) * 64 + lane) * 16);
        bf16x8 bfr[4];
        #pragma unroll
        for (int i = 0; i < 4; ++i) {
            int row = wv * 2 + (i >> 1) + dy;
            int c   = (i & 1) * 16 + l15 + dx;
            bfr[i] = *(const bf16x8*)(actl + row * SLOTB + c * ROWB
                                      + (cinB ^ ((c & 7) << 4)));
        }
        #pragma unroll
        for (int cb = 0; cb < 4; ++cb)
            #pragma unroll
            for (int i = 0; i < 4; ++i)
                acc[cb][i] = __builtin_amdgcn_mfma_f32_16x16x32_bf16(
                    af[cb], bfr[i], acc[cb][i], 0, 0, 0);
    }
}

// MODE 0: init: src=x (NCHW). dst=state0 (NHWC)=conv(x,rw)+rb ;
//         dst2=ICp (NHWC)=0.1*(conv(x,bw)+bb+zz+ab)   [old scattered epilogue]
// MODE 1: iter (NHWC->NHWC): dst = 0.1*conv(nonlin(src),aw)+0.9*src+icp
// MODE 2: final iter: MODE 1 + nonlin, dst written NCHW (contiguous via LDS).
template<int MODE>
__global__ __launch_bounds__(256, 3)
void cenn(const float* __restrict__ src,
          const float* __restrict__ rb, const float* __restrict__ bb,
          const float* __restrict__ zz, const float* __restrict__ ab,
          const float* __restrict__ icp,
          float* __restrict__ dst, float* __restrict__ dst2)
{
    __shared__ __align__(16) char actl[ACTB];
    const int tid  = threadIdx.x;
    const int lane = tid & 63;
    const int wv   = tid >> 6;
    const int l15  = lane & 15;
    const int g4   = lane >> 4;

    // XCD-aware bijective swizzle: 1024 blocks, 128 per XCD chunk (2 images).
    int lin = (blockIdx.z * 16 + blockIdx.y) * 4 + blockIdx.x;
    lin = (lin & 7) * 128 + (lin >> 3);
    const int x0 = (lin & 3) * XS;
    const int y0 = ((lin >> 2) & 15) * GROWS;
    const int n  = lin >> 6;

    if constexpr (MODE == 0) {
        // ---- NCHW staging of x (runs once) ----
        for (int idx = tid; idx < NSLOT * NC * 8; idx += 256) {
            int r   = idx / (NC * 8);
            int rem = idx - r * (NC * 8);
            int cb8 = rem / NC;
            int c   = rem - cb8 * NC;
            int y   = y0 + r - 1;
            int x   = x0 + c - 1;
            uint4 v = {0u, 0u, 0u, 0u};
            if ((unsigned)y < (unsigned)HH && (unsigned)x < (unsigned)WW) {
                const float* p = src + ((size_t)(n * NCH + cb8 * 8) * HH + y) * WW + x;
                unsigned int h[8];
                #pragma unroll
                for (int j = 0; j < 8; ++j)
                    h[j] = f2bf(p[(size_t)j * HH * WW]);
                v.x = h[0] | (h[1] << 16);
                v.y = h[2] | (h[3] << 16);
                v.z = h[4] | (h[5] << 16);
                v.w = h[6] | (h[7] << 16);
            }
            *(uint4*)(actl + r * SLOTB + c * ROWB + ((cb8 * 16) ^ ((c & 7) << 4))) = v;
        }
    } else {
        // ---- NHWC staging: contiguous f32x4 loads, nonlin, pack, ds_write ----
        for (int idx = tid; idx < NSLOT * NC * 16; idx += 256) {
            int r   = idx / (NC * 16);
            int rem = idx - r * (NC * 16);
            int c   = rem >> 4;
            int q   = rem & 15;
            int y   = y0 + r - 1;
            int x   = x0 + c - 1;
            uint2 w2 = {0u, 0u};
            if ((unsigned)y < (unsigned)HH && (unsigned)x < (unsigned)WW) {
                f32x4 v = *(const f32x4*)(src + ((((size_t)n * HH + y) * WW + x) << 6) + q * 4);
                w2.x = f2bf(nonlin(v[0])) | (f2bf(nonlin(v[1])) << 16);
                w2.y = f2bf(nonlin(v[2])) | (f2bf(nonlin(v[3])) << 16);
            }
            *(uint2*)(actl + r * SLOTB + c * ROWB + ((q * 8) ^ ((c & 7) << 4))) = w2;
        }
    }
    __syncthreads();

    f32x4 acc[4][4];
    #pragma unroll
    for (int a = 0; a < 4; ++a)
        #pragma unroll
        for (int b = 0; b < 4; ++b)
            acc[a][b] = (f32x4){0.f, 0.f, 0.f, 0.f};

    conv_tile(actl, g_fw + (MODE == 0 ? 0 : 2 * WSETB), lane, wv, acc);

    if constexpr (MODE == 0) {
        // ---- old (scattered) epilogue, one dispatch only ----
        #pragma unroll
        for (int cb = 0; cb < 4; ++cb)
            #pragma unroll
            for (int i = 0; i < 4; ++i) {
                int y  = y0 + wv * 2 + (i >> 1);
                int x  = x0 + (i & 1) * 16 + l15;
                int c0 = cb * 16 + g4 * 4;
                size_t base = ((((size_t)n * HH + y) * WW + x) << 6) + c0;
                f32x4 o;
                #pragma unroll
                for (int r = 0; r < 4; ++r) o[r] = acc[cb][i][r] + rb[c0 + r];
                *(f32x4*)(dst + base) = o;
            }
        #pragma unroll
        for (int a = 0; a < 4; ++a)
            #pragma unroll
            for (int b = 0; b < 4; ++b)
                acc[a][b] = (f32x4){0.f, 0.f, 0.f, 0.f};
        conv_tile(actl, g_fw + WSETB, lane, wv, acc);
        #pragma unroll
        for (int cb = 0; cb < 4; ++cb)
            #pragma unroll
            for (int i = 0; i < 4; ++i) {
                int y  = y0 + wv * 2 + (i >> 1);
                int x  = x0 + (i & 1) * 16 + l15;
                int c0 = cb * 16 + g4 * 4;
                size_t base = ((((size_t)n * HH + y) * WW + x) << 6) + c0;
                f32x4 o;
                #pragma unroll
                for (int r = 0; r < 4; ++r)
                    o[r] = 0.1f * (acc[cb][i][r] + bb[c0 + r] + zz[c0 + r] + ab[c0 + r]);
                *(f32x4*)(dst2 + base) = o;
            }
    } else {
        // ---- transposed epilogue: 2 chunks of 4 rows (32KB in act LDS) ----
        #pragma unroll
        for (int rs = 0; rs < 2; ++rs) {
            __syncthreads();   // act/prev chunk readers done
            #pragma unroll
            for (int cb = 0; cb < 4; ++cb)
                #pragma unroll
                for (int fr = 0; fr < 2; ++fr) {
                    int i  = rs * 2 + fr;
                    int x  = fr * 16 + l15;
                    int cs = (cb * 16 + g4 * 4) ^ ((x & 7) << 2);
                    *(f32x4*)(actl + (((wv * 32 + x) << 6) + cs) * 4) = acc[cb][i];
                }
            __syncthreads();
            #pragma unroll
            for (int ps = 0; ps < 8; ++ps) {
                int t2   = ps * 256 + tid;
                int q    = t2 & 15;          // channel quad
                int px   = t2 >> 4;          // 0..127
                int x    = px & 31;
                int lrow = px >> 5;          // 0..3
                int cs   = (q * 4) ^ ((x & 7) << 2);
                f32x4 cv = *(const f32x4*)(actl + (((lrow * 32 + x) << 6) + cs) * 4);
                int y  = y0 + lrow * 2 + rs;
                int gx = x0 + x;
                size_t base = ((((size_t)n * HH + y) * WW + gx) << 6) + q * 4;
                f32x4 s = *(const f32x4*)(src + base);
                f32x4 p = *(const f32x4*)(icp + base);
                f32x4 o;
                #pragma unroll
                for (int r = 0; r < 4; ++r)
                    o[r] = 0.1f * cv[r] + 0.9f * s[r] + p[r];
                if constexpr (MODE == 1) {
                    *(f32x4*)(dst + base) = o;
                } else {
                    #pragma unroll
                    for (int r = 0; r < 4; ++r) o[r] = nonlin(o[r]);
                    *(f32x4*)(actl + (((lrow * 32 + x) << 6) + cs) * 4) = o;
                }
            }
            if constexpr (MODE == 2) {
                __syncthreads();
                // channel-major readback -> contiguous NCHW stores
                #pragma unroll
                for (int ps = 0; ps < 8; ++ps) {
                    int xl   = tid & 15;
                    int xf   = (tid >> 4) & 1;
                    int qh   = tid >> 5;             // 0..7
                    int q    = (ps & 1) * 8 + qh;
                    int lrow = ps >> 1;              // 0..3
                    int x    = xf * 16 + xl;
                    int cs   = (q * 4) ^ ((x & 7) << 2);
                    f32x4 v  = *(const f32x4*)(actl + (((lrow * 32 + x) << 6) + cs) * 4);
                    int y  = y0 + lrow * 2 + rs;
                    int gx = x0 + x;
                    #pragma unroll
                    for (int j = 0; j < 4; ++j)
                        dst[((size_t)(n * NCH + q * 4 + j) * HH + y) * WW + gx] = v[j];
                }
            }
        }
    }
}

extern "C" void kernel_launch(void* const* d_in, const int* in_sizes, int n_in,
                              void* d_out, int out_size, void* d_ws, size_t ws_size,
                              hipStream_t stream) {
    const float* x  = (const float*)d_in[0];
    const float* rw = (const float*)d_in[1];
    const float* rb = (const float*)d_in[2];
    const float* aw = (const float*)d_in[3];
    const float* ab = (const float*)d_in[4];
    const float* bw = (const float*)d_in[5];
    const float* bb = (const float*)d_in[6];
    const float* z  = (const float*)d_in[7];
    float* out = (float*)d_out;

    const size_t P = (size_t)16 * NCH * HH * WW;   // 16.78M elems
    float* icp = (float*)d_ws;          // ICp plane, NHWC f32
    float* s1  = icp + P;               // state ping buffer, NHWC f32

    dim3 blk(256, 1, 1), grd(4, 16, 16);   // 1024 blocks

    prep_w<<<dim3(3, 18, 1), blk, 0, stream>>>(rw, bw, aw);
    // state0 (NHWC) -> d_out(raw), ICp (NHWC) -> ws
    cenn<0><<<grd, blk, 0, stream>>>(x, rb, bb, z, ab, nullptr, out, icp);

    // parity: even i reads out, writes s1; odd i reads s1, writes out.
    // i=9 reads s1, writes NCHW final to out.
    for (int i = 0; i < 10; ++i) {
        const float* s = (i & 1) ? s1 : out;
        float*       d = (i & 1) ? out : s1;
        if (i == 9)
            cenn<2><<<grd, blk, 0, stream>>>(s, nullptr, nullptr, nullptr, nullptr, icp, out, nullptr);
        else
            cenn<1><<<grd, blk, 0, stream>>>(s, nullptr, nullptr, nullptr, nullptr, icp, d, nullptr);
    }
}